// Round 21
// baseline (105.177 us; speedup 1.0000x reference)
//
#include <hip/hip_runtime.h>
#include <math.h>

#define INDIM 128
#define HC 256
#define NH 4
#define CAP 128
#define NSHARD 64
#define BROWS 20

typedef unsigned short ushort_t;

__device__ __forceinline__ unsigned int f2bf_u(float f) {
  unsigned int u = __float_as_uint(f);
  return (u + 0x7FFFu + ((u >> 16) & 1u)) >> 16;
}
__device__ __forceinline__ float bf2f(ushort_t u) {
  return __uint_as_float(((unsigned int)u) << 16);
}

// --- GEMM (16x256 tile) with W staged through LDS in 4 k-quarters (r16/r18
//     proven best). Bucket scatter as un-barriered tail; slot = int2(e, src). ---
__global__ __launch_bounds__(256) void gemm_att_bucket_kernel(
    const float* __restrict__ x, const float* __restrict__ W,
    const float* __restrict__ att_s, const float* __restrict__ att_d,
    const int* __restrict__ src, const int* __restrict__ dst,
    int* __restrict__ cnt, int2* __restrict__ bucket, int E, int epb,
    ushort_t* __restrict__ xpb, float* __restrict__ a_src,
    float* __restrict__ a_dst, int N) {
  constexpr int RM = 16;
  __shared__ __align__(16) float xs[RM * INDIM];   // 8 KB
  __shared__ __align__(16) float4 wq[32 * 64];     // 32 KB: one k-quarter of W
  int tid = threadIdx.x;
  int n0 = blockIdx.x * RM;
  int nrows = min(RM, N - n0);

  if (nrows > 0) {  // block-uniform; barriers inside are safe
    if (nrows == RM) {
      const float4* xg = (const float4*)(x + (size_t)n0 * INDIM);
      float4* xs4 = (float4*)xs;
      xs4[tid] = xg[tid];
      xs4[tid + 256] = xg[tid + 256];
    } else {
      for (int i = tid; i < RM * INDIM; i += 256) {
        int r = i / INDIM;
        xs[i] = (r < nrows) ? x[(size_t)(n0 + r) * INDIM + (i % INDIM)] : 0.f;
      }
    }

    int lane = tid & 63;
    int wv = tid >> 6;     // wave owns rows wv*4 .. wv*4+3
    int row0 = wv * 4;

    float4 acc[4];
#pragma unroll
    for (int r = 0; r < 4; ++r) acc[r] = make_float4(0.f, 0.f, 0.f, 0.f);

    const float4* W4 = (const float4*)W;
#pragma unroll 1
    for (int p = 0; p < 4; ++p) {
      if (p) __syncthreads();
      const float4* Wg = W4 + (size_t)p * 2048;
#pragma unroll
      for (int j = 0; j < 8; ++j) wq[tid + j * 256] = Wg[tid + j * 256];
      __syncthreads();
#pragma unroll 1
      for (int c = 0; c < 4; ++c) {
        int kl = c * 8;
        int kg = p * 32 + kl;
        float4 w[8];
#pragma unroll
        for (int j = 0; j < 8; ++j) w[j] = wq[(kl + j) * 64 + lane];
#pragma unroll
        for (int r = 0; r < 4; ++r) {
          float4 xa = *(const float4*)&xs[(row0 + r) * INDIM + kg];
          float4 xb = *(const float4*)&xs[(row0 + r) * INDIM + kg + 4];
          acc[r].x = fmaf(xb.w, w[7].x, fmaf(xb.z, w[6].x, fmaf(xb.y, w[5].x, fmaf(xb.x, w[4].x,
                     fmaf(xa.w, w[3].x, fmaf(xa.z, w[2].x, fmaf(xa.y, w[1].x, fmaf(xa.x, w[0].x, acc[r].x))))))));
          acc[r].y = fmaf(xb.w, w[7].y, fmaf(xb.z, w[6].y, fmaf(xb.y, w[5].y, fmaf(xb.x, w[4].y,
                     fmaf(xa.w, w[3].y, fmaf(xa.z, w[2].y, fmaf(xa.y, w[1].y, fmaf(xa.x, w[0].y, acc[r].y))))))));
          acc[r].z = fmaf(xb.w, w[7].z, fmaf(xb.z, w[6].z, fmaf(xb.y, w[5].z, fmaf(xb.x, w[4].z,
                     fmaf(xa.w, w[3].z, fmaf(xa.z, w[2].z, fmaf(xa.y, w[1].z, fmaf(xa.x, w[0].z, acc[r].z))))))));
          acc[r].w = fmaf(xb.w, w[7].w, fmaf(xb.z, w[6].w, fmaf(xb.y, w[5].w, fmaf(xb.x, w[4].w,
                     fmaf(xa.w, w[3].w, fmaf(xa.z, w[2].w, fmaf(xa.y, w[1].w, fmaf(xa.x, w[0].w, acc[r].w))))))));
        }
      }
    }

    int col = lane * 4;
    float4 as4 = *(const float4*)&att_s[col];
    float4 ad4 = *(const float4*)&att_d[col];
    int h = lane >> 4;
#pragma unroll
    for (int r = 0; r < 4; ++r) {
      int row = row0 + r;
      if (row >= nrows) break;
      float4 a = acc[r];
      uint2 pk;
      pk.x = f2bf_u(a.x) | (f2bf_u(a.y) << 16);
      pk.y = f2bf_u(a.z) | (f2bf_u(a.w) << 16);
      *(uint2*)&xpb[(size_t)(n0 + row) * HC + col] = pk;
      float ps = a.x * as4.x + a.y * as4.y + a.z * as4.z + a.w * as4.w;
      float pd = a.x * ad4.x + a.y * ad4.y + a.z * ad4.z + a.w * ad4.w;
#pragma unroll
      for (int o = 8; o > 0; o >>= 1) {
        ps += __shfl_xor(ps, o);
        pd += __shfl_xor(pd, o);
      }
      if ((lane & 15) == 0) {
        a_src[(n0 + row) * NH + h] = ps;
        a_dst[(n0 + row) * NH + h] = pd;
      }
    }
  }

  // bucket-scatter tail: no barrier after; drain overlaps other blocks
  int e0 = blockIdx.x * epb;
  int e1 = min(e0 + epb, E);
  for (int e = e0 + tid; e < e1; e += 256) {
    int d = dst[e];
    int pos = atomicAdd(&cnt[d], 1);
    if (pos < CAP) {
      int2 v;
      v.x = e;
      v.y = src[e];
      bucket[(size_t)d * CAP + pos] = v;
    }
  }
}

// ------- per-dst-node (block-per-node): softmax + bf16 gather aggregation
//         + alpha scatter + sharded BN1 stats. x1 stored as bf16 (stats
//         accumulated from f32 pre-quantization values -> exact mu/var). -------
__global__ __launch_bounds__(256) void node_kernel(
    const int* __restrict__ cnt, const int2* __restrict__ bucket,
    const float* __restrict__ a_src, const float* __restrict__ a_dst,
    const ushort_t* __restrict__ xpb, const float* __restrict__ bias,
    ushort_t* __restrict__ x1b, float* __restrict__ alpha_out,
    float* __restrict__ shards, int N) {
  int n = blockIdx.x;
  int tid = threadIdx.x;
  int lane = tid & 63, wv = tid >> 6;
  int deg = min(cnt[n], CAP);
  float bv = bias[tid];
  int shb = (n & (NSHARD - 1)) * (2 * HC);
  if (deg == 0) {
    x1b[(size_t)n * HC + tid] = (ushort_t)f2bf_u(bv);
    atomicAdd(&shards[shb + tid], bv);
    atomicAdd(&shards[shb + HC + tid], bv * bv);
    return;
  }
  const int2* brow = bucket + (size_t)n * CAP;

  __shared__ float m_s[NH], d_s[NH];
  __shared__ __align__(16) float alpha_lds[NH * CAP];
  __shared__ __align__(16) int src_lds[CAP];

  // Phase A: wave wv = head wv online softmax; wave 0 caches src indices in LDS
  {
    int h = wv;
    float adst = a_dst[n * NH + h];
    float m = -INFINITY, s = 0.f;
    for (int i = lane; i < deg; i += 64) {
      int sidx = brow[i].y;
      if (h == 0) src_lds[i] = sidx;
      float l = a_src[sidx * NH + h] + adst;
      l = (l >= 0.f) ? l : 0.2f * l;
      if (l > m) { s = s * __expf(m - l) + 1.f; m = l; }
      else s += __expf(l - m);
    }
#pragma unroll
    for (int o = 32; o > 0; o >>= 1) {
      float m2 = __shfl_xor(m, o);
      float s2 = __shfl_xor(s, o);
      float M = fmaxf(m, m2);
      float sa = (m > -INFINITY) ? s * __expf(m - M) : 0.f;
      float sb = (m2 > -INFINITY) ? s2 * __expf(m2 - M) : 0.f;
      m = M; s = sa + sb;
    }
    if (lane == 0) { m_s[h] = m; d_s[h] = s + 1e-16f; }
  }
  __syncthreads();

  float m_r[NH], dinv_r[NH], adst_r[NH];
#pragma unroll
  for (int h = 0; h < NH; ++h) {
    m_r[h] = m_s[h];
    dinv_r[h] = 1.0f / d_s[h];
    adst_r[h] = a_dst[n * NH + h];
  }

  // alpha: one edge per thread (deg <= CAP=128 < 256); scatter to out + LDS
  int cpad = (deg + 3) & ~3;
  if (tid < deg) {
    int sidx = src_lds[tid];
    float4 as4 = *(const float4*)&a_src[sidx * NH];
    const float* ap = (const float*)&as4;
    float4 av;
    float* avp = (float*)&av;
#pragma unroll
    for (int h = 0; h < NH; ++h) {
      float l = ap[h] + adst_r[h];
      l = (l >= 0.f) ? l : 0.2f * l;
      float a = __expf(l - m_r[h]) * dinv_r[h];
      alpha_lds[h * CAP + tid] = a;
      avp[h] = a;
    }
    *(float4*)&alpha_out[(size_t)brow[tid].x * NH] = av;
  } else if (tid < cpad) {
    src_lds[tid] = 0;
#pragma unroll
    for (int h = 0; h < NH; ++h) alpha_lds[h * CAP + tid] = 0.f;
  }
  __syncthreads();

  float acc0 = 0.f, acc1 = 0.f, acc2 = 0.f, acc3 = 0.f;
  int hbase = wv * CAP;
  for (int i = 0; i < cpad; i += 4) {
    float4 a4 = *(const float4*)&alpha_lds[hbase + i];
    int4 s4 = *(const int4*)&src_lds[i];
    ushort_t u0 = xpb[(size_t)s4.x * HC + tid];
    ushort_t u1 = xpb[(size_t)s4.y * HC + tid];
    ushort_t u2 = xpb[(size_t)s4.z * HC + tid];
    ushort_t u3 = xpb[(size_t)s4.w * HC + tid];
    acc0 = fmaf(a4.x, bf2f(u0), acc0);
    acc1 = fmaf(a4.y, bf2f(u1), acc1);
    acc2 = fmaf(a4.z, bf2f(u2), acc2);
    acc3 = fmaf(a4.w, bf2f(u3), acc3);
  }
  float v = (acc0 + acc1) + (acc2 + acc3) + bv;
  x1b[(size_t)n * HC + tid] = (ushort_t)f2bf_u(v);
  atomicAdd(&shards[shb + tid], v);
  atomicAdd(&shards[shb + HC + tid], v * v);
}

// ------- BN2 stats: reduce BN1 shards in-register, then pass over elu(bn1(x1)) -------
__global__ __launch_bounds__(256) void bn_stats2_kernel(
    const ushort_t* __restrict__ x1b, const float* __restrict__ shards,
    const float* __restrict__ gamma, const float* __restrict__ beta,
    float* __restrict__ sums2, int N) {
  int t = threadIdx.x;
  float s1 = 0.f, q1 = 0.f;
#pragma unroll
  for (int k = 0; k < NSHARD; ++k) {
    s1 += shards[k * (2 * HC) + t];
    q1 += shards[k * (2 * HC) + HC + t];
  }
  float mu = s1 * (1.f / N);
  float var = q1 * (1.f / N) - mu * mu;
  float inv = rsqrtf(var + 1e-5f);
  float g = gamma[t], b = beta[t];
  int r0 = blockIdx.x * BROWS;
  int rend = min(r0 + BROWS, N);
  float s = 0.f, q = 0.f;
  for (int r = r0; r < rend; ++r) {
    float v = bf2f(x1b[(size_t)r * HC + t]);
    float x2 = fmaf((v - mu) * inv, g, b);
    float e = x2 > 0.f ? x2 : expm1f(x2);
    s += e; q = fmaf(e, e, q);
  }
  atomicAdd(&sums2[t], s);
  atomicAdd(&sums2[HC + t], q);
}

// ------- final: shard-reduce BN1, read sums2, apply both BNs, transposed store -------
__global__ __launch_bounds__(256) void bn_final_kernel(
    const ushort_t* __restrict__ x1b, const float* __restrict__ shards,
    const float* __restrict__ sums2, const float* __restrict__ gamma,
    const float* __restrict__ beta, float* __restrict__ out, int N) {
  int t = threadIdx.x;
  float s1 = 0.f, q1 = 0.f;
#pragma unroll
  for (int k = 0; k < NSHARD; ++k) {
    s1 += shards[k * (2 * HC) + t];
    q1 += shards[k * (2 * HC) + HC + t];
  }
  float mu1 = s1 * (1.f / N);
  float var1 = q1 * (1.f / N) - mu1 * mu1;
  float inv1 = rsqrtf(var1 + 1e-5f);
  float mu2 = sums2[t] * (1.f / N);
  float var2 = sums2[HC + t] * (1.f / N) - mu2 * mu2;
  float inv2 = rsqrtf(var2 + 1e-5f);
  float g = gamma[t], b = beta[t];
  int h = t >> 6, c = t & 63;
  int r0 = blockIdx.x * BROWS;
  int rend = min(r0 + BROWS, N);
  for (int r = r0; r < rend; ++r) {
    float v = bf2f(x1b[(size_t)r * HC + t]);
    float x2 = fmaf((v - mu1) * inv1, g, b);
    float e = x2 > 0.f ? x2 : expm1f(x2);
    out[(size_t)h * N * 64 + (size_t)r * 64 + c] = fmaf((e - mu2) * inv2, g, b);
  }
}

extern "C" void kernel_launch(void* const* d_in, const int* in_sizes, int n_in,
                              void* d_out, int out_size, void* d_ws, size_t ws_size,
                              hipStream_t stream) {
  const float* x     = (const float*)d_in[0];
  const int*   edge  = (const int*)d_in[1];
  const float* W     = (const float*)d_in[2];
  const float* att_s = (const float*)d_in[3];
  const float* att_d = (const float*)d_in[4];
  const float* bias  = (const float*)d_in[5];
  const float* gamma = (const float*)d_in[6];
  const float* beta  = (const float*)d_in[7];

  int N = in_sizes[0] / INDIM;
  int E = in_sizes[1] / 2;
  const int* src = edge;
  const int* dst = edge + E;

  char* ws = (char*)d_ws;
  size_t o = 0;
  auto alloc = [&](size_t bytes) {
    void* p = ws + o;
    o += (bytes + 255) & ~(size_t)255;
    return p;
  };
  ushort_t* xpb     = (ushort_t*)alloc((size_t)N * HC * 2);
  ushort_t* x1b     = (ushort_t*)alloc((size_t)N * HC * 2);
  float* a_src      = (float*)alloc((size_t)N * NH * 4);
  float* a_dst      = (float*)alloc((size_t)N * NH * 4);
  // zero-init region: cnt + shards + sums2 contiguous -> single memset
  char*  zbase      = (char*)alloc(0);
  int*   cnt        = (int*)alloc((size_t)N * 4);
  float* shards     = (float*)alloc((size_t)NSHARD * 2 * HC * 4);
  float* sums2      = (float*)alloc(2 * HC * 4);
  size_t zbytes     = (size_t)((char*)alloc(0) - zbase);
  int2*  bucket     = (int2*)alloc((size_t)N * CAP * 8);

  float* out_heads = (float*)d_out;
  float* out_alpha = out_heads + (size_t)NH * N * 64;

  hipMemsetAsync(zbase, 0, zbytes, stream);

  int gblocks = (N + 15) / 16;
  int epb = (E + gblocks - 1) / gblocks;
  gemm_att_bucket_kernel<<<gblocks, 256, 0, stream>>>(
      x, W, att_s, att_d, src, dst, cnt, bucket, E, epb, xpb, a_src, a_dst, N);
  node_kernel<<<N, 256, 0, stream>>>(cnt, bucket, a_src, a_dst, xpb, bias,
                                     x1b, out_alpha, shards, N);
  int bnb = (N + BROWS - 1) / BROWS;
  bn_stats2_kernel<<<bnb, 256, 0, stream>>>(x1b, shards, gamma, beta, sums2, N);
  bn_final_kernel<<<bnb, 256, 0, stream>>>(x1b, shards, sums2, gamma, beta,
                                           out_heads, N);
}

// Round 22
// 103.464 us; speedup vs baseline: 1.0166x; 1.0166x over previous
//
#include <hip/hip_runtime.h>
#include <math.h>

#define INDIM 128
#define HC 256
#define NH 4
#define CAP 128
#define NSHARD 64
#define BROWS 20

typedef unsigned short ushort_t;

__device__ __forceinline__ unsigned int f2bf_u(float f) {
  unsigned int u = __float_as_uint(f);
  return (u + 0x7FFFu + ((u >> 16) & 1u)) >> 16;
}
__device__ __forceinline__ float bf2f(ushort_t u) {
  return __uint_as_float(((unsigned int)u) << 16);
}

// --- GEMM (16x256 tile) with W staged through LDS in 4 k-quarters (r16/r18
//     proven best). Bucket scatter as un-barriered tail; slot = int2(e, src). ---
__global__ __launch_bounds__(256) void gemm_att_bucket_kernel(
    const float* __restrict__ x, const float* __restrict__ W,
    const float* __restrict__ att_s, const float* __restrict__ att_d,
    const int* __restrict__ src, const int* __restrict__ dst,
    int* __restrict__ cnt, int2* __restrict__ bucket, int E, int epb,
    ushort_t* __restrict__ xpb, float* __restrict__ a_src,
    float* __restrict__ a_dst, int N) {
  constexpr int RM = 16;
  __shared__ __align__(16) float xs[RM * INDIM];   // 8 KB
  __shared__ __align__(16) float4 wq[32 * 64];     // 32 KB: one k-quarter of W
  int tid = threadIdx.x;
  int n0 = blockIdx.x * RM;
  int nrows = min(RM, N - n0);

  if (nrows > 0) {  // block-uniform; barriers inside are safe
    if (nrows == RM) {
      const float4* xg = (const float4*)(x + (size_t)n0 * INDIM);
      float4* xs4 = (float4*)xs;
      xs4[tid] = xg[tid];
      xs4[tid + 256] = xg[tid + 256];
    } else {
      for (int i = tid; i < RM * INDIM; i += 256) {
        int r = i / INDIM;
        xs[i] = (r < nrows) ? x[(size_t)(n0 + r) * INDIM + (i % INDIM)] : 0.f;
      }
    }

    int lane = tid & 63;
    int wv = tid >> 6;     // wave owns rows wv*4 .. wv*4+3
    int row0 = wv * 4;

    float4 acc[4];
#pragma unroll
    for (int r = 0; r < 4; ++r) acc[r] = make_float4(0.f, 0.f, 0.f, 0.f);

    const float4* W4 = (const float4*)W;
#pragma unroll 1
    for (int p = 0; p < 4; ++p) {
      if (p) __syncthreads();
      const float4* Wg = W4 + (size_t)p * 2048;
#pragma unroll
      for (int j = 0; j < 8; ++j) wq[tid + j * 256] = Wg[tid + j * 256];
      __syncthreads();
#pragma unroll 1
      for (int c = 0; c < 4; ++c) {
        int kl = c * 8;
        int kg = p * 32 + kl;
        float4 w[8];
#pragma unroll
        for (int j = 0; j < 8; ++j) w[j] = wq[(kl + j) * 64 + lane];
#pragma unroll
        for (int r = 0; r < 4; ++r) {
          float4 xa = *(const float4*)&xs[(row0 + r) * INDIM + kg];
          float4 xb = *(const float4*)&xs[(row0 + r) * INDIM + kg + 4];
          acc[r].x = fmaf(xb.w, w[7].x, fmaf(xb.z, w[6].x, fmaf(xb.y, w[5].x, fmaf(xb.x, w[4].x,
                     fmaf(xa.w, w[3].x, fmaf(xa.z, w[2].x, fmaf(xa.y, w[1].x, fmaf(xa.x, w[0].x, acc[r].x))))))));
          acc[r].y = fmaf(xb.w, w[7].y, fmaf(xb.z, w[6].y, fmaf(xb.y, w[5].y, fmaf(xb.x, w[4].y,
                     fmaf(xa.w, w[3].y, fmaf(xa.z, w[2].y, fmaf(xa.y, w[1].y, fmaf(xa.x, w[0].y, acc[r].y))))))));
          acc[r].z = fmaf(xb.w, w[7].z, fmaf(xb.z, w[6].z, fmaf(xb.y, w[5].z, fmaf(xb.x, w[4].z,
                     fmaf(xa.w, w[3].z, fmaf(xa.z, w[2].z, fmaf(xa.y, w[1].z, fmaf(xa.x, w[0].z, acc[r].z))))))));
          acc[r].w = fmaf(xb.w, w[7].w, fmaf(xb.z, w[6].w, fmaf(xb.y, w[5].w, fmaf(xb.x, w[4].w,
                     fmaf(xa.w, w[3].w, fmaf(xa.z, w[2].w, fmaf(xa.y, w[1].w, fmaf(xa.x, w[0].w, acc[r].w))))))));
        }
      }
    }

    int col = lane * 4;
    float4 as4 = *(const float4*)&att_s[col];
    float4 ad4 = *(const float4*)&att_d[col];
    int h = lane >> 4;
#pragma unroll
    for (int r = 0; r < 4; ++r) {
      int row = row0 + r;
      if (row >= nrows) break;
      float4 a = acc[r];
      uint2 pk;
      pk.x = f2bf_u(a.x) | (f2bf_u(a.y) << 16);
      pk.y = f2bf_u(a.z) | (f2bf_u(a.w) << 16);
      *(uint2*)&xpb[(size_t)(n0 + row) * HC + col] = pk;
      float ps = a.x * as4.x + a.y * as4.y + a.z * as4.z + a.w * as4.w;
      float pd = a.x * ad4.x + a.y * ad4.y + a.z * ad4.z + a.w * ad4.w;
#pragma unroll
      for (int o = 8; o > 0; o >>= 1) {
        ps += __shfl_xor(ps, o);
        pd += __shfl_xor(pd, o);
      }
      if ((lane & 15) == 0) {
        a_src[(n0 + row) * NH + h] = ps;
        a_dst[(n0 + row) * NH + h] = pd;
      }
    }
  }

  // bucket-scatter tail: no barrier after; drain overlaps other blocks
  int e0 = blockIdx.x * epb;
  int e1 = min(e0 + epb, E);
  for (int e = e0 + tid; e < e1; e += 256) {
    int d = dst[e];
    int pos = atomicAdd(&cnt[d], 1);
    if (pos < CAP) {
      int2 v;
      v.x = e;
      v.y = src[e];
      bucket[(size_t)d * CAP + pos] = v;
    }
  }
}

// ------- per-dst-node (block-per-node): softmax + bf16 gather aggregation
//         + alpha scatter + sharded BN1 stats -------
__global__ __launch_bounds__(256) void node_kernel(
    const int* __restrict__ cnt, const int2* __restrict__ bucket,
    const float* __restrict__ a_src, const float* __restrict__ a_dst,
    const ushort_t* __restrict__ xpb, const float* __restrict__ bias,
    float* __restrict__ x1, float* __restrict__ alpha_out,
    float* __restrict__ shards, int N) {
  int n = blockIdx.x;
  int tid = threadIdx.x;
  int lane = tid & 63, wv = tid >> 6;
  int deg = min(cnt[n], CAP);
  float bv = bias[tid];
  int shb = (n & (NSHARD - 1)) * (2 * HC);
  if (deg == 0) {
    x1[(size_t)n * HC + tid] = bv;
    atomicAdd(&shards[shb + tid], bv);
    atomicAdd(&shards[shb + HC + tid], bv * bv);
    return;
  }
  const int2* brow = bucket + (size_t)n * CAP;

  __shared__ float m_s[NH], d_s[NH];
  __shared__ __align__(16) float alpha_lds[NH * CAP];
  __shared__ __align__(16) int src_lds[CAP];

  // Phase A: wave wv = head wv online softmax; wave 0 caches src indices in LDS
  {
    int h = wv;
    float adst = a_dst[n * NH + h];
    float m = -INFINITY, s = 0.f;
    for (int i = lane; i < deg; i += 64) {
      int sidx = brow[i].y;
      if (h == 0) src_lds[i] = sidx;
      float l = a_src[sidx * NH + h] + adst;
      l = (l >= 0.f) ? l : 0.2f * l;
      if (l > m) { s = s * __expf(m - l) + 1.f; m = l; }
      else s += __expf(l - m);
    }
#pragma unroll
    for (int o = 32; o > 0; o >>= 1) {
      float m2 = __shfl_xor(m, o);
      float s2 = __shfl_xor(s, o);
      float M = fmaxf(m, m2);
      float sa = (m > -INFINITY) ? s * __expf(m - M) : 0.f;
      float sb = (m2 > -INFINITY) ? s2 * __expf(m2 - M) : 0.f;
      m = M; s = sa + sb;
    }
    if (lane == 0) { m_s[h] = m; d_s[h] = s + 1e-16f; }
  }
  __syncthreads();

  float m_r[NH], dinv_r[NH], adst_r[NH];
#pragma unroll
  for (int h = 0; h < NH; ++h) {
    m_r[h] = m_s[h];
    dinv_r[h] = 1.0f / d_s[h];
    adst_r[h] = a_dst[n * NH + h];
  }

  // alpha: one edge per thread (deg <= CAP=128 < 256); scatter to out + LDS
  int cpad = (deg + 3) & ~3;
  if (tid < deg) {
    int sidx = src_lds[tid];
    float4 as4 = *(const float4*)&a_src[sidx * NH];
    const float* ap = (const float*)&as4;
    float4 av;
    float* avp = (float*)&av;
#pragma unroll
    for (int h = 0; h < NH; ++h) {
      float l = ap[h] + adst_r[h];
      l = (l >= 0.f) ? l : 0.2f * l;
      float a = __expf(l - m_r[h]) * dinv_r[h];
      alpha_lds[h * CAP + tid] = a;
      avp[h] = a;
    }
    *(float4*)&alpha_out[(size_t)brow[tid].x * NH] = av;
  } else if (tid < cpad) {
    src_lds[tid] = 0;
#pragma unroll
    for (int h = 0; h < NH; ++h) alpha_lds[h * CAP + tid] = 0.f;
  }
  __syncthreads();

  float acc0 = 0.f, acc1 = 0.f, acc2 = 0.f, acc3 = 0.f;
  int hbase = wv * CAP;
  for (int i = 0; i < cpad; i += 4) {
    float4 a4 = *(const float4*)&alpha_lds[hbase + i];
    int4 s4 = *(const int4*)&src_lds[i];
    ushort_t u0 = xpb[(size_t)s4.x * HC + tid];
    ushort_t u1 = xpb[(size_t)s4.y * HC + tid];
    ushort_t u2 = xpb[(size_t)s4.z * HC + tid];
    ushort_t u3 = xpb[(size_t)s4.w * HC + tid];
    acc0 = fmaf(a4.x, bf2f(u0), acc0);
    acc1 = fmaf(a4.y, bf2f(u1), acc1);
    acc2 = fmaf(a4.z, bf2f(u2), acc2);
    acc3 = fmaf(a4.w, bf2f(u3), acc3);
  }
  float v = (acc0 + acc1) + (acc2 + acc3) + bv;
  x1[(size_t)n * HC + tid] = v;
  atomicAdd(&shards[shb + tid], v);
  atomicAdd(&shards[shb + HC + tid], v * v);
}

// ------- BN2 stats: reduce BN1 shards in-register, then pass over elu(bn1(x1)) -------
__global__ __launch_bounds__(256) void bn_stats2_kernel(
    const float* __restrict__ x1, const float* __restrict__ shards,
    const float* __restrict__ gamma, const float* __restrict__ beta,
    float* __restrict__ sums2, int N) {
  int t = threadIdx.x;
  float s1 = 0.f, q1 = 0.f;
#pragma unroll
  for (int k = 0; k < NSHARD; ++k) {
    s1 += shards[k * (2 * HC) + t];
    q1 += shards[k * (2 * HC) + HC + t];
  }
  float mu = s1 * (1.f / N);
  float var = q1 * (1.f / N) - mu * mu;
  float inv = rsqrtf(var + 1e-5f);
  float g = gamma[t], b = beta[t];
  int r0 = blockIdx.x * BROWS;
  int rend = min(r0 + BROWS, N);
  float s = 0.f, q = 0.f;
  for (int r = r0; r < rend; ++r) {
    float v = x1[(size_t)r * HC + t];
    float x2 = fmaf((v - mu) * inv, g, b);
    float e = x2 > 0.f ? x2 : expm1f(x2);
    s += e; q = fmaf(e, e, q);
  }
  atomicAdd(&sums2[t], s);
  atomicAdd(&sums2[HC + t], q);
}

// ------- final: shard-reduce BN1, read sums2, apply both BNs, transposed store -------
__global__ __launch_bounds__(256) void bn_final_kernel(
    const float* __restrict__ x1, const float* __restrict__ shards,
    const float* __restrict__ sums2, const float* __restrict__ gamma,
    const float* __restrict__ beta, float* __restrict__ out, int N) {
  int t = threadIdx.x;
  float s1 = 0.f, q1 = 0.f;
#pragma unroll
  for (int k = 0; k < NSHARD; ++k) {
    s1 += shards[k * (2 * HC) + t];
    q1 += shards[k * (2 * HC) + HC + t];
  }
  float mu1 = s1 * (1.f / N);
  float var1 = q1 * (1.f / N) - mu1 * mu1;
  float inv1 = rsqrtf(var1 + 1e-5f);
  float mu2 = sums2[t] * (1.f / N);
  float var2 = sums2[HC + t] * (1.f / N) - mu2 * mu2;
  float inv2 = rsqrtf(var2 + 1e-5f);
  float g = gamma[t], b = beta[t];
  int h = t >> 6, c = t & 63;
  int r0 = blockIdx.x * BROWS;
  int rend = min(r0 + BROWS, N);
  for (int r = r0; r < rend; ++r) {
    float v = x1[(size_t)r * HC + t];
    float x2 = fmaf((v - mu1) * inv1, g, b);
    float e = x2 > 0.f ? x2 : expm1f(x2);
    out[(size_t)h * N * 64 + (size_t)r * 64 + c] = fmaf((e - mu2) * inv2, g, b);
  }
}

extern "C" void kernel_launch(void* const* d_in, const int* in_sizes, int n_in,
                              void* d_out, int out_size, void* d_ws, size_t ws_size,
                              hipStream_t stream) {
  const float* x     = (const float*)d_in[0];
  const int*   edge  = (const int*)d_in[1];
  const float* W     = (const float*)d_in[2];
  const float* att_s = (const float*)d_in[3];
  const float* att_d = (const float*)d_in[4];
  const float* bias  = (const float*)d_in[5];
  const float* gamma = (const float*)d_in[6];
  const float* beta  = (const float*)d_in[7];

  int N = in_sizes[0] / INDIM;
  int E = in_sizes[1] / 2;
  const int* src = edge;
  const int* dst = edge + E;

  char* ws = (char*)d_ws;
  size_t o = 0;
  auto alloc = [&](size_t bytes) {
    void* p = ws + o;
    o += (bytes + 255) & ~(size_t)255;
    return p;
  };
  ushort_t* xpb     = (ushort_t*)alloc((size_t)N * HC * 2);
  float* x1         = (float*)alloc((size_t)N * HC * 4);
  float* a_src      = (float*)alloc((size_t)N * NH * 4);
  float* a_dst      = (float*)alloc((size_t)N * NH * 4);
  // zero-init region: cnt + shards + sums2 contiguous -> single memset
  char*  zbase      = (char*)alloc(0);
  int*   cnt        = (int*)alloc((size_t)N * 4);
  float* shards     = (float*)alloc((size_t)NSHARD * 2 * HC * 4);
  float* sums2      = (float*)alloc(2 * HC * 4);
  size_t zbytes     = (size_t)((char*)alloc(0) - zbase);
  int2*  bucket     = (int2*)alloc((size_t)N * CAP * 8);

  float* out_heads = (float*)d_out;
  float* out_alpha = out_heads + (size_t)NH * N * 64;

  hipMemsetAsync(zbase, 0, zbytes, stream);

  int gblocks = (N + 15) / 16;
  int epb = (E + gblocks - 1) / gblocks;
  gemm_att_bucket_kernel<<<gblocks, 256, 0, stream>>>(
      x, W, att_s, att_d, src, dst, cnt, bucket, E, epb, xpb, a_src, a_dst, N);
  node_kernel<<<N, 256, 0, stream>>>(cnt, bucket, a_src, a_dst, xpb, bias,
                                     x1, out_alpha, shards, N);
  int bnb = (N + BROWS - 1) / BROWS;
  bn_stats2_kernel<<<bnb, 256, 0, stream>>>(x1, shards, gamma, beta, sums2, N);
  bn_final_kernel<<<bnb, 256, 0, stream>>>(x1, shards, sums2, gamma, beta,
                                           out_heads, N);
}